// Round 7
// baseline (451.748 us; speedup 1.0000x reference)
//
#include <hip/hip_runtime.h>
#include <hip/hip_bf16.h>

// Correlation layer: out[b, i*41+j, y, x] = (1/576) * sum_c in1[b,c,y,x]*in2[b,c,y-dy,x-dx]
// dx = 2i-20, dy = 2j-20 (i = m/41, j = m%41), zero padding outside.
// b=4, c=64, h=96, w=160, D=41. Output 413 MB fp32.
//
// R7 = R6 (448us; A-hoist WIN -46us) with ONE change: gd staged in bf16 ->
// LDS 49.9KB -> 36.3KB -> 4 blocks/CU (16 waves), __launch_bounds__(256,4).
// Rationale: R4 tested this occupancy bump PRE-R6 when the serialized A-load
// chain dominated (wrong regime -> null). R6 removed that chain; remaining
// stalls are short ds_read/L2 latency chains that more TLP can hide.
// Numerics: R4 passed with identical absmax (4.88e-4) using bf16 gd.
// Ledger: R1 grid-swap -37; R2 j-loop +23 (rev); R3 swizzle 0; R4 occupancy 0
// (wrong regime); R5 store path 0; R6 A-hoist -46 (WIN).

#define B_ 4
#define C_ 64
#define H_ 96
#define W_ 160
#define DD 41
#define HW_ (H_*W_)
#define RS 72            // s2 LDS row stride (64 ch + 8 pad) -> 144 B rows, 16B-aligned
#define GSH 162          // gd16 row stride (ushorts): even -> dword-aligned rows

typedef __bf16 bf16x8 __attribute__((ext_vector_type(8)));
typedef float  f32x4  __attribute__((ext_vector_type(4)));
typedef float  f32x2  __attribute__((ext_vector_type(2)));
typedef unsigned int u32x4 __attribute__((ext_vector_type(4)));

// ---------------- Pass 1: NCHW fp32 -> NHWC bf16 ----------------
__global__ void to_nhwc(const float* __restrict__ s1, const float* __restrict__ s2,
                        ushort* __restrict__ d1, ushort* __restrict__ d2) {
    int p = blockIdx.x * 256 + threadIdx.x;            // pixel id in [0, B*H*W)
    const float* src = blockIdx.y ? s2 : s1;
    ushort* dst = blockIdx.y ? d2 : d1;
    int b = p / HW_;
    int rem = p - b * HW_;
    const float* sp = src + (size_t)b * (C_ * HW_) + rem;
    unsigned words[32];
#pragma unroll
    for (int k = 0; k < 32; ++k) {
        union { float f; unsigned u; } lo, hi;
        lo.f = sp[(size_t)(2 * k) * HW_];              // coalesced across lanes
        hi.f = sp[(size_t)(2 * k + 1) * HW_];
        unsigned rl = (lo.u + 0x7FFFu + ((lo.u >> 16) & 1u)) >> 16;         // RNE
        unsigned rh = (hi.u + 0x7FFFu + ((hi.u >> 16) & 1u)) & 0xFFFF0000u; // RNE
        words[k] = rl | rh;
    }
    u32x4* dp = (u32x4*)(dst + (size_t)p * C_);
#pragma unroll
    for (int k = 0; k < 8; ++k) {
        u32x4 v = { words[4 * k], words[4 * k + 1], words[4 * k + 2], words[4 * k + 3] };
        dp[k] = v;
    }
}

// ---------------- Pass 2: correlation ----------------
__global__ __launch_bounds__(256, 4) void corr_kernel(const ushort* __restrict__ in1w,
                                                      const ushort* __restrict__ in2w,
                                                      float* __restrict__ out) {
    __shared__ ushort s2[2 * 80 * RS];    // in2 row, parity-split: [par][u>>1][72] = 23040 B
    __shared__ ushort gd16[DD * GSH];     // banded Gram in bf16, 13284 B (total 36324 -> 4 blk/CU)

    const int y   = blockIdx.x;           // y fastest: concurrent blocks write adjacent rows
    const int j   = blockIdx.y;           // dy index
    const int b   = blockIdx.z;
    const int tid = threadIdx.x;
    const int lane = tid & 63;
    const int w    = tid >> 6;            // wave id 0..3
    const int quad = lane >> 4;
    const int l15  = lane & 15;
    const int y2 = y + 20 - 2 * j;
    const bool valid_row = (y2 >= 0) && (y2 < H_);

    if (valid_row) {
        // ---- A-fragment hoist (R6 WIN): wave w's pairs span mi in {mi0,mi0+1,mi0+2}.
        // Issued FIRST so L2/L3 latency hides under staging+barrier.
        const ushort* a_base = in1w + (size_t)((b * H_ + y) * W_) * C_;
        const int mi0 = (w * 10) >> 2;
        bf16x8 A0[3], A1[3];
#pragma unroll
        for (int k = 0; k < 3; ++k) {
            int mi  = mi0 + k;
            int par = (mi >= 5) ? 1 : 0;
            int x0  = (mi - 5 * par) * 32;
            int xa  = x0 + par + 2 * l15;     // A[m=l15][ch], x = x0+par+2*m
            const bf16x8* aptr = (const bf16x8*)(const void*)(a_base + xa * C_ + quad * 8);
            A0[k] = aptr[0];                  // ch quad*8 .. +7
            A1[k] = aptr[4];                  // ch quad*8+32 .. +7
        }

        // ---- stage in2 row y2 (160 px * 64 ch bf16 = 20 KB) into parity-split LDS
        const uint4* src = (const uint4*)(in2w + (size_t)((b * H_ + y2) * W_) * C_);
#pragma unroll
        for (int it = 0; it < 5; ++it) {
            int cidx = it * 256 + tid;            // 1280 chunks of 16 B
            int u  = cidx >> 3;
            int co = (cidx & 7) * 8;
            uint4 v = src[cidx];                  // fully coalesced
            *(uint4*)&s2[((u & 1) * 80 + (u >> 1)) * RS + co] = v;
        }
        __syncthreads();

        // ---- MFMA Gram tiles: 40 (Mtile,Ntile) products, 10 per wave.
        // k = (t + 2*(w&1))>>2 is compile-time after unroll -> A0/A1 stay in regs.
#define MFMA_BODY(OFF)                                                               \
        _Pragma("unroll")                                                            \
        for (int t = 0; t < 10; ++t) {                                               \
            const int k   = (t + 2 * (OFF)) >> 2;                                    \
            const int mi  = mi0 + k;                                                 \
            const int nt  = (2 * w + t) & 3;       /* p&3, p = w*10+t */             \
            const int par = (mi >= 5) ? 1 : 0;                                       \
            const int x0  = (mi - 5 * par) * 32;                                     \
            const int u   = x0 + par - 60 + 32 * nt + 2 * l15;                       \
            bf16x8 b0 = {}, b1 = {};                                                 \
            if (u >= 0 && u < W_) {                                                  \
                const bf16x8* bptr =                                                 \
                    (const bf16x8*)(const void*)&s2[((u & 1) * 80 + (u >> 1)) * RS + quad * 8]; \
                b0 = bptr[0];                                                        \
                b1 = bptr[4];                                                        \
            }                                                                        \
            f32x4 acc = {};                                                          \
            acc = __builtin_amdgcn_mfma_f32_16x16x32_bf16(A0[k], b0, acc, 0, 0, 0);  \
            acc = __builtin_amdgcn_mfma_f32_16x16x32_bf16(A1[k], b1, acc, 0, 0, 0);  \
            _Pragma("unroll")                                                        \
            for (int r = 0; r < 4; ++r) {                                            \
                int mx = quad * 4 + r;                                               \
                int i  = mx - l15 - 16 * nt + 40;                                    \
                if (i >= 0 && i <= 40) {                                             \
                    int x = x0 + par + 2 * mx;                                       \
                    union { float f; unsigned u32v; } cv; cv.f = acc[r];             \
                    unsigned rr = (cv.u32v + 0x7FFFu + ((cv.u32v >> 16) & 1u)) >> 16;\
                    gd16[i * GSH + x] = (ushort)rr;  /* each (i,x) written once */   \
                }                                                                    \
            }                                                                        \
        }

        if ((w & 1) == 0) { MFMA_BODY(0) } else { MFMA_BODY(1) }
#undef MFMA_BODY
        __syncthreads();
    }

    // ---- output pass: out[b, i*41+j, y, 0..159]; dword = 2 bf16 -> plain dwordx2
    const float scale = 1.0f / 576.0f;
    for (int i = w; i < DD; i += 4) {
        float* op = out + ((size_t)(b * (DD * DD) + i * DD + j) * H_ + y) * W_;
        if (valid_row) {
            const ushort* g = &gd16[i * GSH];
            unsigned d0 = *(const unsigned*)&g[2 * lane];          // x = 2*lane, 2*lane+1
            union { unsigned u; float f; } c0, c1;
            c0.u = d0 << 16;
            c1.u = d0 & 0xFFFF0000u;
            f32x2 v0; v0[0] = c0.f * scale; v0[1] = c1.f * scale;
            *(f32x2*)(op + 2 * lane) = v0;
            if (lane < 16) {
                unsigned d1 = *(const unsigned*)&g[2 * (64 + lane)]; // x = 128+2*lane, +1
                union { unsigned u; float f; } c2, c3;
                c2.u = d1 << 16;
                c3.u = d1 & 0xFFFF0000u;
                f32x2 v1; v1[0] = c2.f * scale; v1[1] = c3.f * scale;
                *(f32x2*)(op + 128 + 2 * lane) = v1;
            }
        } else {
            f32x2 z = {};
            *(f32x2*)(op + 2 * lane) = z;
            if (lane < 16) *(f32x2*)(op + 128 + 2 * lane) = z;
        }
    }
}

extern "C" void kernel_launch(void* const* d_in, const int* in_sizes, int n_in,
                              void* d_out, int out_size, void* d_ws, size_t ws_size,
                              hipStream_t stream) {
    const float* in1 = (const float*)d_in[0];
    const float* in2 = (const float*)d_in[1];
    float* out = (float*)d_out;
    ushort* w1 = (ushort*)d_ws;                      // 4*96*160*64 bf16 = 7.86 MB
    ushort* w2 = w1 + (size_t)B_ * H_ * W_ * C_;     // second tensor
    // Pass 1: transpose+cast both inputs (B*H*W = 61440 pixels, 240 blocks x 2)
    to_nhwc<<<dim3((B_ * HW_) / 256, 2), 256, 0, stream>>>(in1, in2, w1, w2);
    // Pass 2: one block per (y, j, b) -- y fastest for write locality
    corr_kernel<<<dim3(H_, DD, B_), 256, 0, stream>>>(w1, w2, out);
}